// Round 6
// baseline (308.284 us; speedup 1.0000x reference)
//
#include <hip/hip_runtime.h>
#include <hip/hip_bf16.h>
#include <math.h>

#define NN_ 2048
#define CC_ 256
#define KC_ 128
#define KF_ 16

typedef __attribute__((ext_vector_type(8))) short short8;
typedef __attribute__((ext_vector_type(4))) float f32x4;

__device__ __forceinline__ unsigned int mono_u(float f) {
  unsigned int u = __float_as_uint(f);
  return (u & 0x80000000u) ? ~u : (u | 0x80000000u);
}
__device__ __forceinline__ float inv_mono(unsigned int m) {
  unsigned int u = (m & 0x80000000u) ? (m ^ 0x80000000u) : ~m;
  return __uint_as_float(u);
}

__device__ __forceinline__ void gload_lds16(const void* g, void* l) {
  __builtin_amdgcn_global_load_lds(
      (const __attribute__((address_space(1))) void*)g,
      (__attribute__((address_space(3))) void*)l, 16, 0, 0);
}

__device__ __forceinline__ unsigned short bf16_bits(float v) {
  __hip_bfloat16 h = __float2bfloat16(v);  // RNE
  return *(unsigned short*)&h;
}
__device__ __forceinline__ float bf16_val(unsigned short u) {
  __hip_bfloat16 h = *(__hip_bfloat16*)&u;
  return __bfloat162float(h);
}

// Projection via split-bf16 MFMA (3 terms), fp32->h/l split fused into LDS
// staging. 64x64 tile, K=256, z folded into blockIdx.y. (unchanged from R4)
__global__ __launch_bounds__(256) void proj_mfma_kernel(
    const float* __restrict__ fa, const float* __restrict__ fb,
    const float* __restrict__ Wq, const float* __restrict__ bq,
    const float* __restrict__ Wk, const float* __restrict__ bk,
    __hip_bfloat16* __restrict__ qh, __hip_bfloat16* __restrict__ ql,
    __hip_bfloat16* __restrict__ kh, __hip_bfloat16* __restrict__ kl)
{
  __shared__ short Ah[64 * 32], Al[64 * 32], Bh[64 * 32], Bl[64 * 32];
  const int m0 = blockIdx.y * 64;
  const int z = m0 >> 12;
  const int mloc = m0 & 4095;
  const float* A = z ? fb : fa;
  const float* W = z ? Wk : Wq;
  const float* bias = z ? bk : bq;
  __hip_bfloat16* oh = z ? kh : qh;
  __hip_bfloat16* ol = z ? kl : ql;
  const int n0 = blockIdx.x * 64;
  const int tid = threadIdx.x;
  const int lane = tid & 63, wave = tid >> 6;
  const int wm = (wave & 1) << 5, wn = (wave >> 1) << 5;
  const int fm = lane & 15, quad = lane >> 4;

  const int r = tid >> 3;
  const int r2 = r + 32;
  const int c4 = (tid & 7) << 2;
  const int ck = c4 >> 3;
  const int soff = c4 & 7;
  const int iA0 = (((r << 2) + (ck ^ ((r >> 1) & 3))) << 3) + soff;
  const int iA1 = (((r2 << 2) + (ck ^ ((r2 >> 1) & 3))) << 3) + soff;

  f32x4 acc[2][2];
#pragma unroll
  for (int i = 0; i < 2; ++i)
#pragma unroll
    for (int j = 0; j < 2; ++j) acc[i][j] = (f32x4){0.f, 0.f, 0.f, 0.f};

  for (int kb = 0; kb < CC_; kb += 32) {
    float4 va0 = *(const float4*)(A + (long)(mloc + r) * CC_ + kb + c4);
    float4 va1 = *(const float4*)(A + (long)(mloc + r2) * CC_ + kb + c4);
    float4 vb0 = *(const float4*)(W + (long)(n0 + r) * CC_ + kb + c4);
    float4 vb1 = *(const float4*)(W + (long)(n0 + r2) * CC_ + kb + c4);
    __syncthreads();
    {
      const float* pv;
      float4 vv;
      vv = va0; pv = (const float*)&vv;
      uint2 hu, lu;
      unsigned short h0 = bf16_bits(pv[0]), h1 = bf16_bits(pv[1]),
                     h2 = bf16_bits(pv[2]), h3 = bf16_bits(pv[3]);
      hu.x = (unsigned)h0 | ((unsigned)h1 << 16);
      hu.y = (unsigned)h2 | ((unsigned)h3 << 16);
      lu.x = (unsigned)bf16_bits(pv[0] - bf16_val(h0)) |
             ((unsigned)bf16_bits(pv[1] - bf16_val(h1)) << 16);
      lu.y = (unsigned)bf16_bits(pv[2] - bf16_val(h2)) |
             ((unsigned)bf16_bits(pv[3] - bf16_val(h3)) << 16);
      *(uint2*)&Ah[iA0] = hu; *(uint2*)&Al[iA0] = lu;
      vv = va1; pv = (const float*)&vv;
      h0 = bf16_bits(pv[0]); h1 = bf16_bits(pv[1]);
      h2 = bf16_bits(pv[2]); h3 = bf16_bits(pv[3]);
      hu.x = (unsigned)h0 | ((unsigned)h1 << 16);
      hu.y = (unsigned)h2 | ((unsigned)h3 << 16);
      lu.x = (unsigned)bf16_bits(pv[0] - bf16_val(h0)) |
             ((unsigned)bf16_bits(pv[1] - bf16_val(h1)) << 16);
      lu.y = (unsigned)bf16_bits(pv[2] - bf16_val(h2)) |
             ((unsigned)bf16_bits(pv[3] - bf16_val(h3)) << 16);
      *(uint2*)&Ah[iA1] = hu; *(uint2*)&Al[iA1] = lu;
      vv = vb0; pv = (const float*)&vv;
      h0 = bf16_bits(pv[0]); h1 = bf16_bits(pv[1]);
      h2 = bf16_bits(pv[2]); h3 = bf16_bits(pv[3]);
      hu.x = (unsigned)h0 | ((unsigned)h1 << 16);
      hu.y = (unsigned)h2 | ((unsigned)h3 << 16);
      lu.x = (unsigned)bf16_bits(pv[0] - bf16_val(h0)) |
             ((unsigned)bf16_bits(pv[1] - bf16_val(h1)) << 16);
      lu.y = (unsigned)bf16_bits(pv[2] - bf16_val(h2)) |
             ((unsigned)bf16_bits(pv[3] - bf16_val(h3)) << 16);
      *(uint2*)&Bh[iA0] = hu; *(uint2*)&Bl[iA0] = lu;
      vv = vb1; pv = (const float*)&vv;
      h0 = bf16_bits(pv[0]); h1 = bf16_bits(pv[1]);
      h2 = bf16_bits(pv[2]); h3 = bf16_bits(pv[3]);
      hu.x = (unsigned)h0 | ((unsigned)h1 << 16);
      hu.y = (unsigned)h2 | ((unsigned)h3 << 16);
      lu.x = (unsigned)bf16_bits(pv[0] - bf16_val(h0)) |
             ((unsigned)bf16_bits(pv[1] - bf16_val(h1)) << 16);
      lu.y = (unsigned)bf16_bits(pv[2] - bf16_val(h2)) |
             ((unsigned)bf16_bits(pv[3] - bf16_val(h3)) << 16);
      *(uint2*)&Bh[iA1] = hu; *(uint2*)&Bl[iA1] = lu;
    }
    __syncthreads();
    short8 afh[2], afl[2], bfh[2], bfl[2];
#pragma unroll
    for (int t = 0; t < 2; ++t) {
      int m = wm + (t << 4) + fm;
      int sa = ((m << 2) + (quad ^ ((m >> 1) & 3))) << 3;
      afh[t] = *(const short8*)&Ah[sa];
      afl[t] = *(const short8*)&Al[sa];
      int n = wn + (t << 4) + fm;
      int sb = ((n << 2) + (quad ^ ((n >> 1) & 3))) << 3;
      bfh[t] = *(const short8*)&Bh[sb];
      bfl[t] = *(const short8*)&Bl[sb];
    }
#pragma unroll
    for (int mi = 0; mi < 2; ++mi)
#pragma unroll
      for (int ni = 0; ni < 2; ++ni) {
        acc[mi][ni] = __builtin_amdgcn_mfma_f32_16x16x32_bf16(
            afh[mi], bfh[ni], acc[mi][ni], 0, 0, 0);
        acc[mi][ni] = __builtin_amdgcn_mfma_f32_16x16x32_bf16(
            afh[mi], bfl[ni], acc[mi][ni], 0, 0, 0);
        acc[mi][ni] = __builtin_amdgcn_mfma_f32_16x16x32_bf16(
            afl[mi], bfh[ni], acc[mi][ni], 0, 0, 0);
      }
  }

#pragma unroll
  for (int mi = 0; mi < 2; ++mi)
#pragma unroll
    for (int ni = 0; ni < 2; ++ni) {
      int nn = n0 + wn + (ni << 4) + fm;
      float bval = bias[nn];
      int mrow = mloc + wm + (mi << 4) + (quad << 2);
#pragma unroll
      for (int reg = 0; reg < 4; ++reg) {
        float v = acc[mi][ni][reg] + bval;
        __hip_bfloat16 h = __float2bfloat16(v);
        long idx = (long)(mrow + reg) * CC_ + nn;
        oh[idx] = h;
        ol[idx] = __float2bfloat16(v - __bfloat162float(h));
      }
    }
}

// sim[z] = qh@kh^T + qh@kl^T + ql@kh^T, 3 terms interleaved, 48 MFMA per
// barrier pair. (unchanged from R4)
__global__ __launch_bounds__(256) void sim_mfma_kernel(
    const __hip_bfloat16* __restrict__ qh, const __hip_bfloat16* __restrict__ ql,
    const __hip_bfloat16* __restrict__ kh, const __hip_bfloat16* __restrict__ kl,
    float* __restrict__ sim)
{
  __shared__ short Ah[128 * 32], Al[128 * 32], Bh[128 * 32], Bl[128 * 32];
  const int z = blockIdx.z;
  const long off = (long)z * NN_ * CC_;
  const int m0 = blockIdx.y * 128, n0 = blockIdx.x * 128;
  const int tid = threadIdx.x;
  const int lane = tid & 63, wave = tid >> 6;
  const int wm = (wave & 1) << 6, wn = (wave >> 1) << 6;
  const int fm = lane & 15, quad = lane >> 4;

  const int r0 = tid >> 2, r1 = r0 + 64;
  const int c0 = (((tid & 3) ^ ((r0 >> 1) & 3)) << 3);
  const int c1 = (((tid & 3) ^ ((r1 >> 1) & 3)) << 3);
  const long lo0 = (long)tid * 8, lo1 = ((long)tid + 256) * 8;
  const long gA0 = (long)(m0 + r0) * CC_ + c0 + off;
  const long gA1 = (long)(m0 + r1) * CC_ + c1 + off;
  const long gB0 = (long)(n0 + r0) * CC_ + c0 + off;
  const long gB1 = (long)(n0 + r1) * CC_ + c1 + off;

  f32x4 acc[4][4];
#pragma unroll
  for (int i = 0; i < 4; ++i)
#pragma unroll
    for (int j = 0; j < 4; ++j) acc[i][j] = (f32x4){0.f, 0.f, 0.f, 0.f};

  for (int kb = 0; kb < CC_; kb += 32) {
    gload_lds16(qh + gA0 + kb, Ah + lo0);
    gload_lds16(qh + gA1 + kb, Ah + lo1);
    gload_lds16(ql + gA0 + kb, Al + lo0);
    gload_lds16(ql + gA1 + kb, Al + lo1);
    gload_lds16(kh + gB0 + kb, Bh + lo0);
    gload_lds16(kh + gB1 + kb, Bh + lo1);
    gload_lds16(kl + gB0 + kb, Bl + lo0);
    gload_lds16(kl + gB1 + kb, Bl + lo1);
    __syncthreads();
    short8 afh[4], afl[4], bfh[4], bfl[4];
#pragma unroll
    for (int t = 0; t < 4; ++t) {
      int m = wm + (t << 4) + fm;
      int sa = ((m << 2) + (quad ^ ((m >> 1) & 3))) << 3;
      afh[t] = *(const short8*)&Ah[sa];
      afl[t] = *(const short8*)&Al[sa];
      int n = wn + (t << 4) + fm;
      int sb = ((n << 2) + (quad ^ ((n >> 1) & 3))) << 3;
      bfh[t] = *(const short8*)&Bh[sb];
      bfl[t] = *(const short8*)&Bl[sb];
    }
#pragma unroll
    for (int mi = 0; mi < 4; ++mi)
#pragma unroll
      for (int ni = 0; ni < 4; ++ni) {
        acc[mi][ni] = __builtin_amdgcn_mfma_f32_16x16x32_bf16(
            afh[mi], bfh[ni], acc[mi][ni], 0, 0, 0);
        acc[mi][ni] = __builtin_amdgcn_mfma_f32_16x16x32_bf16(
            afh[mi], bfl[ni], acc[mi][ni], 0, 0, 0);
        acc[mi][ni] = __builtin_amdgcn_mfma_f32_16x16x32_bf16(
            afl[mi], bfh[ni], acc[mi][ni], 0, 0, 0);
      }
    __syncthreads();
  }

  float* Cp = sim + (long)z * NN_ * NN_;
#pragma unroll
  for (int mi = 0; mi < 4; ++mi) {
#pragma unroll
    for (int ni = 0; ni < 4; ++ni) {
      int m = m0 + wm + (mi << 4) + (quad << 2);
      int n = n0 + wn + (ni << 4) + fm;
      float* p = Cp + (long)m * NN_ + n;
      p[0] = acc[mi][ni][0];
      p[NN_] = acc[mi][ni][1];
      p[2 * NN_] = acc[mi][ni][2];
      p[3 * NN_] = acc[mi][ni][3];
    }
  }
}

// One WAVE per row, zero barriers. Coarse top-128 via ONE 2048-bin (11-bit
// prefix) u16-packed LDS histogram: fine bins spread the Gaussian mass over
// ~40 distinct words (low same-address multiplicity), one pass instead of
// four. Suffix-scan finds the rank-128 bin B; bins>B collected via ~2
// atomics/lane; the boundary bin's members are extracted EXACTLY from the
// register-resident keys by wave-argmax with a per-lane taken-mask (full-key
// desc, idx asc -> exact jax tie semantics, no tie-count cap).
__global__ __launch_bounds__(256) void select_scatter_kernel(
    const float* __restrict__ sim, const float* __restrict__ dirs_a,
    const float* __restrict__ dirs_b, float* __restrict__ P)
{
  const int wave = threadIdx.x >> 6;
  const int lane = threadIdx.x & 63;
  const int row = (blockIdx.x << 2) | wave;
  const int b = row >> 11;
  const float* srow = sim + (long)row * NN_;
  float* prow = P + (long)row * NN_;

  __shared__ unsigned int histbuf_s[4][1024];  // hist, later reused as rowbuf
  __shared__ unsigned int ckey_s[4][KC_];
  __shared__ int cidx_s[4][KC_];
  __shared__ float outp_s[4][KF_];
  __shared__ int outj_s[4][KF_];
  __shared__ int cnt_s[4];

  unsigned int* histw = histbuf_s[wave];
  float* rowbuf = (float*)histbuf_s[wave];
  unsigned int* ckey = ckey_s[wave];
  int* cidx = cidx_s[wave];
  float* outp = outp_s[wave];
  int* outj = outj_s[wave];

  // row -> 32 monotone keys per lane (coalesced float4 loads)
  unsigned int key[32];
#pragma unroll
  for (int c = 0; c < 8; ++c) {
    float4 v = *(const float4*)(srow + (c << 8) + (lane << 2));
    key[(c << 2) + 0] = mono_u(v.x);
    key[(c << 2) + 1] = mono_u(v.y);
    key[(c << 2) + 2] = mono_u(v.z);
    key[(c << 2) + 3] = mono_u(v.w);
  }

  // ---- zero packed histogram (1024 words = 2048 u16 bins), 16 words/lane
  {
    uint4 z4; z4.x = z4.y = z4.z = z4.w = 0u;
#pragma unroll
    for (int t = 0; t < 4; ++t)
      *(uint4*)&histw[(lane << 4) + (t << 2)] = z4;
  }
  // ---- accumulate: bin = key >> 21; word = bin>>1, half = bin&1
#pragma unroll
  for (int i = 0; i < 32; ++i) {
    unsigned int bin = key[i] >> 21;
    atomicAdd(&histw[bin >> 1], 1u << ((bin & 1) << 4));
  }
  // ---- read back: lane owns words [lane*16, lane*16+16) = bins [32L,32L+32)
  unsigned int c16[32];
#pragma unroll
  for (int t = 0; t < 4; ++t) {
    uint4 w = *(const uint4*)&histw[(lane << 4) + (t << 2)];
    c16[(t << 3) + 0] = w.x & 0xFFFFu; c16[(t << 3) + 1] = w.x >> 16;
    c16[(t << 3) + 2] = w.y & 0xFFFFu; c16[(t << 3) + 3] = w.y >> 16;
    c16[(t << 3) + 4] = w.z & 0xFFFFu; c16[(t << 3) + 5] = w.z >> 16;
    c16[(t << 3) + 6] = w.w & 0xFFFFu; c16[(t << 3) + 7] = w.w >> 16;
  }
  unsigned int tot = 0;
#pragma unroll
  for (int i = 0; i < 32; ++i) tot += c16[i];
  // wave suffix-exclusive sum of tot (higher lanes = higher bins)
  unsigned int incl = tot;
#pragma unroll
  for (int off = 1; off < 64; off <<= 1) {
    unsigned int y = __shfl_down(incl, off);
    incl += (lane + off < 64) ? y : 0u;
  }
  const unsigned int sufx = incl - tot;
  // find largest bin B with count_ge(B) >= 128 (scan lane-local bins high->low)
  int li = -1;
  unsigned int run = 0, cge_l = 0, cB_l = 0;
  for (int i = 31; i >= 0; --i) {
    run += c16[i];
    if (run + sufx >= (unsigned)KC_) {
      li = i; cge_l = run + sufx; cB_l = c16[i];
      break;
    }
  }
  unsigned long long mb = __ballot(li >= 0);  // nonzero: lane0 qualifies at bin0
  const int src = 63 - __clzll(mb);
  const unsigned int B = (unsigned)__shfl((lane << 5) + li, src);
  const unsigned int cge = __shfl(cge_l, src);
  const unsigned int cB = __shfl(cB_l, src);
  const int ngt = (int)(cge - cB);       // keys in bins > B  (< 128)
  const int need_rem = KC_ - ngt;        // 1..cB

  // ---- collect bins > B (guaranteed members; order irrelevant) ----
  if (lane == 0) cnt_s[wave] = 0;        // in-order DS within the wave
#pragma unroll
  for (int i = 0; i < 32; ++i) {
    if ((key[i] >> 21) > B) {
      int col = ((i >> 2) << 8) + (lane << 2) + (i & 3);
      int p = atomicAdd(&cnt_s[wave], 1);
      ckey[p] = key[i];
      cidx[p] = col;
    }
  }
  // ---- exact extraction of need_rem largest from bin B (register keys) ----
  unsigned int taken = 0u;
  for (int r = 0; r < need_rem; ++r) {
    unsigned int bk = 0u; int bi = 0x7FFFFFFF, bslot = -1;
#pragma unroll
    for (int i = 0; i < 32; ++i) {
      if (!((taken >> i) & 1u) && (key[i] >> 21) == B) {
        int col = ((i >> 2) << 8) + (lane << 2) + (i & 3);
        if (key[i] > bk || (key[i] == bk && col < bi)) {
          bk = key[i]; bi = col; bslot = i;
        }
      }
    }
    int bl = lane;
#pragma unroll
    for (int off = 32; off > 0; off >>= 1) {
      unsigned int ok = __shfl_down(bk, off);
      int oi = __shfl_down(bi, off);
      int ol = __shfl_down(bl, off);
      if (ok > bk || (ok == bk && oi < bi)) { bk = ok; bi = oi; bl = ol; }
    }
    bk = __shfl(bk, 0); bi = __shfl(bi, 0); bl = __shfl(bl, 0);
    if (lane == 0) { ckey[ngt + r] = bk; cidx[ngt + r] = bi; }
    if (lane == bl && bslot >= 0) taken |= 1u << bslot;
  }

  // ---- angular mask (2 candidates/lane) ----
  const long dbase = (long)row * 3;
  const float dax = dirs_a[dbase + 0], day = dirs_a[dbase + 1],
              daz = dirs_a[dbase + 2];
  int j0 = cidx[lane], j1 = cidx[lane + 64];
  float va0 = inv_mono(ckey[lane]), va1 = inv_mono(ckey[lane + 64]);
  const float* db0 = dirs_b + ((long)(b << 11) + j0) * 3;
  float ca0 = dax * db0[0] + day * db0[1] + daz * db0[2];
  const float* db1 = dirs_b + ((long)(b << 11) + j1) * 3;
  float ca1 = dax * db1[0] + day * db1[1] + daz * db1[2];
  bool lm0 = ca0 >= 0.96592582628906831f;
  bool lm1 = ca1 >= 0.96592582628906831f;
  int ecnt = __popcll(__ballot(lm0)) + __popcll(__ballot(lm1));
  const bool all = (ecnt == 0);
  float v0 = (all || lm0) ? va0 : -INFINITY;
  float v1 = (all || lm1) ? va1 : -INFINITY;
  const int elig = all ? KC_ : ecnt;
  const int nk = elig < KF_ ? elig : KF_;

  // ---- fine top-16: iterative wave-wide argmax extraction ----
  for (int r = 0; r < nk; ++r) {
    float bvv; int bj, bs;
    if (v1 > v0 || (v1 == v0 && j1 < j0)) { bvv = v1; bj = j1; bs = lane + 64; }
    else { bvv = v0; bj = j0; bs = lane; }
#pragma unroll
    for (int off = 32; off > 0; off >>= 1) {
      float ov = __shfl_down(bvv, off);
      int oj = __shfl_down(bj, off);
      int os = __shfl_down(bs, off);
      if (ov > bvv || (ov == bvv && oj < bj)) { bvv = ov; bj = oj; bs = os; }
    }
    bvv = __shfl(bvv, 0); bj = __shfl(bj, 0); bs = __shfl(bs, 0);
    if (lane == 0) { outj[r] = bj; outp[r] = bvv; }
    if (bs == lane) v0 = -INFINITY;
    if (bs == lane + 64) v1 = -INFINITY;
  }

  // ---- softmax over kept logits (parallel over 16 lanes) ----
  const float invT = 1.0f / 0.07f;
  float mxl = outp[0] * invT;  // extraction is descending -> slot 0 is max
  float e = 0.f;
  int myj = 0;
  if (lane < nk) {
    e = __expf(outp[lane] * invT - mxl);
    myj = outj[lane];
  }
  float ssum = e;
#pragma unroll
  for (int off = 32; off > 0; off >>= 1) ssum += __shfl_xor(ssum, off);
  float pr = e / ssum;
  float s2 = pr;
#pragma unroll
  for (int off = 32; off > 0; off >>= 1) s2 += __shfl_xor(s2, off);
  const float outv = pr * (1.0f / (s2 + 1e-8f));

  // ---- zero + scatter + coalesced writeback, two 4KB halves (hist reused) --
#pragma unroll
  for (int h = 0; h < 2; ++h) {
    float4 zf; zf.x = zf.y = zf.z = zf.w = 0.f;
#pragma unroll
    for (int q = 0; q < 4; ++q)
      *(float4*)&rowbuf[(q << 8) + (lane << 2)] = zf;
    if (lane < nk && (myj >> 10) == h) rowbuf[myj & 1023] = outv;
#pragma unroll
    for (int q = 0; q < 4; ++q) {
      float4 v = *(const float4*)&rowbuf[(q << 8) + (lane << 2)];
      *(float4*)(prow + (h << 10) + (q << 8) + (lane << 2)) = v;
    }
  }
}

extern "C" void kernel_launch(void* const* d_in, const int* in_sizes, int n_in,
                              void* d_out, int out_size, void* d_ws, size_t ws_size,
                              hipStream_t stream) {
  (void)in_sizes; (void)n_in; (void)out_size; (void)ws_size;
  const float* feat_a = (const float*)d_in[0];
  const float* feat_b = (const float*)d_in[1];
  const float* dirs_a = (const float*)d_in[2];
  const float* dirs_b = (const float*)d_in[3];
  const float* Wq = (const float*)d_in[4];
  const float* bq = (const float*)d_in[5];
  const float* Wk = (const float*)d_in[6];
  const float* bk = (const float*)d_in[7];
  float* P = (float*)d_out;

  __hip_bfloat16* qh = (__hip_bfloat16*)d_ws;
  __hip_bfloat16* ql = qh + (long)2 * NN_ * CC_;
  __hip_bfloat16* kh = ql + (long)2 * NN_ * CC_;
  __hip_bfloat16* kl = kh + (long)2 * NN_ * CC_;
  float* sim = (float*)(kl + (long)2 * NN_ * CC_);

  proj_mfma_kernel<<<dim3(CC_ / 64, (4 * NN_) / 64), 256, 0, stream>>>(
      feat_a, feat_b, Wq, bq, Wk, bk, qh, ql, kh, kl);

  sim_mfma_kernel<<<dim3(NN_ / 128, NN_ / 128, 2), 256, 0, stream>>>(
      qh, ql, kh, kl, sim);

  select_scatter_kernel<<<dim3((2 * NN_) / 4), 256, 0, stream>>>(
      sim, dirs_a, dirs_b, P);
}

// Round 7
// 139.591 us; speedup vs baseline: 2.2085x; 2.2085x over previous
//
#include <hip/hip_runtime.h>
#include <hip/hip_bf16.h>
#include <math.h>

#define NN_ 2048
#define CC_ 256
#define KC_ 128
#define KF_ 16
#define EQCAP 64

typedef __attribute__((ext_vector_type(8))) short short8;
typedef __attribute__((ext_vector_type(4))) float f32x4;

__device__ __forceinline__ unsigned int mono_u(float f) {
  unsigned int u = __float_as_uint(f);
  return (u & 0x80000000u) ? ~u : (u | 0x80000000u);
}
__device__ __forceinline__ float inv_mono(unsigned int m) {
  unsigned int u = (m & 0x80000000u) ? (m ^ 0x80000000u) : ~m;
  return __uint_as_float(u);
}

__device__ __forceinline__ void gload_lds16(const void* g, void* l) {
  __builtin_amdgcn_global_load_lds(
      (const __attribute__((address_space(1))) void*)g,
      (__attribute__((address_space(3))) void*)l, 16, 0, 0);
}

__device__ __forceinline__ unsigned short bf16_bits(float v) {
  __hip_bfloat16 h = __float2bfloat16(v);  // RNE
  return *(unsigned short*)&h;
}
__device__ __forceinline__ float bf16_val(unsigned short u) {
  __hip_bfloat16 h = *(__hip_bfloat16*)&u;
  return __bfloat162float(h);
}

// Projection via split-bf16 MFMA (3 terms), fp32->h/l split fused into LDS
// staging. 64x64 tile, K=256, z folded into blockIdx.y. (unchanged from R4)
__global__ __launch_bounds__(256) void proj_mfma_kernel(
    const float* __restrict__ fa, const float* __restrict__ fb,
    const float* __restrict__ Wq, const float* __restrict__ bq,
    const float* __restrict__ Wk, const float* __restrict__ bk,
    __hip_bfloat16* __restrict__ qh, __hip_bfloat16* __restrict__ ql,
    __hip_bfloat16* __restrict__ kh, __hip_bfloat16* __restrict__ kl)
{
  __shared__ short Ah[64 * 32], Al[64 * 32], Bh[64 * 32], Bl[64 * 32];
  const int m0 = blockIdx.y * 64;
  const int z = m0 >> 12;
  const int mloc = m0 & 4095;
  const float* A = z ? fb : fa;
  const float* W = z ? Wk : Wq;
  const float* bias = z ? bk : bq;
  __hip_bfloat16* oh = z ? kh : qh;
  __hip_bfloat16* ol = z ? kl : ql;
  const int n0 = blockIdx.x * 64;
  const int tid = threadIdx.x;
  const int lane = tid & 63, wave = tid >> 6;
  const int wm = (wave & 1) << 5, wn = (wave >> 1) << 5;
  const int fm = lane & 15, quad = lane >> 4;

  const int r = tid >> 3;
  const int r2 = r + 32;
  const int c4 = (tid & 7) << 2;
  const int ck = c4 >> 3;
  const int soff = c4 & 7;
  const int iA0 = (((r << 2) + (ck ^ ((r >> 1) & 3))) << 3) + soff;
  const int iA1 = (((r2 << 2) + (ck ^ ((r2 >> 1) & 3))) << 3) + soff;

  f32x4 acc[2][2];
#pragma unroll
  for (int i = 0; i < 2; ++i)
#pragma unroll
    for (int j = 0; j < 2; ++j) acc[i][j] = (f32x4){0.f, 0.f, 0.f, 0.f};

  for (int kb = 0; kb < CC_; kb += 32) {
    float4 va0 = *(const float4*)(A + (long)(mloc + r) * CC_ + kb + c4);
    float4 va1 = *(const float4*)(A + (long)(mloc + r2) * CC_ + kb + c4);
    float4 vb0 = *(const float4*)(W + (long)(n0 + r) * CC_ + kb + c4);
    float4 vb1 = *(const float4*)(W + (long)(n0 + r2) * CC_ + kb + c4);
    __syncthreads();
    {
      const float* pv;
      float4 vv;
      vv = va0; pv = (const float*)&vv;
      uint2 hu, lu;
      unsigned short h0 = bf16_bits(pv[0]), h1 = bf16_bits(pv[1]),
                     h2 = bf16_bits(pv[2]), h3 = bf16_bits(pv[3]);
      hu.x = (unsigned)h0 | ((unsigned)h1 << 16);
      hu.y = (unsigned)h2 | ((unsigned)h3 << 16);
      lu.x = (unsigned)bf16_bits(pv[0] - bf16_val(h0)) |
             ((unsigned)bf16_bits(pv[1] - bf16_val(h1)) << 16);
      lu.y = (unsigned)bf16_bits(pv[2] - bf16_val(h2)) |
             ((unsigned)bf16_bits(pv[3] - bf16_val(h3)) << 16);
      *(uint2*)&Ah[iA0] = hu; *(uint2*)&Al[iA0] = lu;
      vv = va1; pv = (const float*)&vv;
      h0 = bf16_bits(pv[0]); h1 = bf16_bits(pv[1]);
      h2 = bf16_bits(pv[2]); h3 = bf16_bits(pv[3]);
      hu.x = (unsigned)h0 | ((unsigned)h1 << 16);
      hu.y = (unsigned)h2 | ((unsigned)h3 << 16);
      lu.x = (unsigned)bf16_bits(pv[0] - bf16_val(h0)) |
             ((unsigned)bf16_bits(pv[1] - bf16_val(h1)) << 16);
      lu.y = (unsigned)bf16_bits(pv[2] - bf16_val(h2)) |
             ((unsigned)bf16_bits(pv[3] - bf16_val(h3)) << 16);
      *(uint2*)&Ah[iA1] = hu; *(uint2*)&Al[iA1] = lu;
      vv = vb0; pv = (const float*)&vv;
      h0 = bf16_bits(pv[0]); h1 = bf16_bits(pv[1]);
      h2 = bf16_bits(pv[2]); h3 = bf16_bits(pv[3]);
      hu.x = (unsigned)h0 | ((unsigned)h1 << 16);
      hu.y = (unsigned)h2 | ((unsigned)h3 << 16);
      lu.x = (unsigned)bf16_bits(pv[0] - bf16_val(h0)) |
             ((unsigned)bf16_bits(pv[1] - bf16_val(h1)) << 16);
      lu.y = (unsigned)bf16_bits(pv[2] - bf16_val(h2)) |
             ((unsigned)bf16_bits(pv[3] - bf16_val(h3)) << 16);
      *(uint2*)&Bh[iA0] = hu; *(uint2*)&Bl[iA0] = lu;
      vv = vb1; pv = (const float*)&vv;
      h0 = bf16_bits(pv[0]); h1 = bf16_bits(pv[1]);
      h2 = bf16_bits(pv[2]); h3 = bf16_bits(pv[3]);
      hu.x = (unsigned)h0 | ((unsigned)h1 << 16);
      hu.y = (unsigned)h2 | ((unsigned)h3 << 16);
      lu.x = (unsigned)bf16_bits(pv[0] - bf16_val(h0)) |
             ((unsigned)bf16_bits(pv[1] - bf16_val(h1)) << 16);
      lu.y = (unsigned)bf16_bits(pv[2] - bf16_val(h2)) |
             ((unsigned)bf16_bits(pv[3] - bf16_val(h3)) << 16);
      *(uint2*)&Bh[iA1] = hu; *(uint2*)&Bl[iA1] = lu;
    }
    __syncthreads();
    short8 afh[2], afl[2], bfh[2], bfl[2];
#pragma unroll
    for (int t = 0; t < 2; ++t) {
      int m = wm + (t << 4) + fm;
      int sa = ((m << 2) + (quad ^ ((m >> 1) & 3))) << 3;
      afh[t] = *(const short8*)&Ah[sa];
      afl[t] = *(const short8*)&Al[sa];
      int n = wn + (t << 4) + fm;
      int sb = ((n << 2) + (quad ^ ((n >> 1) & 3))) << 3;
      bfh[t] = *(const short8*)&Bh[sb];
      bfl[t] = *(const short8*)&Bl[sb];
    }
#pragma unroll
    for (int mi = 0; mi < 2; ++mi)
#pragma unroll
      for (int ni = 0; ni < 2; ++ni) {
        acc[mi][ni] = __builtin_amdgcn_mfma_f32_16x16x32_bf16(
            afh[mi], bfh[ni], acc[mi][ni], 0, 0, 0);
        acc[mi][ni] = __builtin_amdgcn_mfma_f32_16x16x32_bf16(
            afh[mi], bfl[ni], acc[mi][ni], 0, 0, 0);
        acc[mi][ni] = __builtin_amdgcn_mfma_f32_16x16x32_bf16(
            afl[mi], bfh[ni], acc[mi][ni], 0, 0, 0);
      }
  }

#pragma unroll
  for (int mi = 0; mi < 2; ++mi)
#pragma unroll
    for (int ni = 0; ni < 2; ++ni) {
      int nn = n0 + wn + (ni << 4) + fm;
      float bval = bias[nn];
      int mrow = mloc + wm + (mi << 4) + (quad << 2);
#pragma unroll
      for (int reg = 0; reg < 4; ++reg) {
        float v = acc[mi][ni][reg] + bval;
        __hip_bfloat16 h = __float2bfloat16(v);
        long idx = (long)(mrow + reg) * CC_ + nn;
        oh[idx] = h;
        ol[idx] = __float2bfloat16(v - __bfloat162float(h));
      }
    }
}

// sim[z] = qh@kh^T + qh@kl^T + ql@kh^T, 3 terms interleaved, 48 MFMA per
// barrier pair. (unchanged from R4)
__global__ __launch_bounds__(256) void sim_mfma_kernel(
    const __hip_bfloat16* __restrict__ qh, const __hip_bfloat16* __restrict__ ql,
    const __hip_bfloat16* __restrict__ kh, const __hip_bfloat16* __restrict__ kl,
    float* __restrict__ sim)
{
  __shared__ short Ah[128 * 32], Al[128 * 32], Bh[128 * 32], Bl[128 * 32];
  const int z = blockIdx.z;
  const long off = (long)z * NN_ * CC_;
  const int m0 = blockIdx.y * 128, n0 = blockIdx.x * 128;
  const int tid = threadIdx.x;
  const int lane = tid & 63, wave = tid >> 6;
  const int wm = (wave & 1) << 6, wn = (wave >> 1) << 6;
  const int fm = lane & 15, quad = lane >> 4;

  const int r0 = tid >> 2, r1 = r0 + 64;
  const int c0 = (((tid & 3) ^ ((r0 >> 1) & 3)) << 3);
  const int c1 = (((tid & 3) ^ ((r1 >> 1) & 3)) << 3);
  const long lo0 = (long)tid * 8, lo1 = ((long)tid + 256) * 8;
  const long gA0 = (long)(m0 + r0) * CC_ + c0 + off;
  const long gA1 = (long)(m0 + r1) * CC_ + c1 + off;
  const long gB0 = (long)(n0 + r0) * CC_ + c0 + off;
  const long gB1 = (long)(n0 + r1) * CC_ + c1 + off;

  f32x4 acc[4][4];
#pragma unroll
  for (int i = 0; i < 4; ++i)
#pragma unroll
    for (int j = 0; j < 4; ++j) acc[i][j] = (f32x4){0.f, 0.f, 0.f, 0.f};

  for (int kb = 0; kb < CC_; kb += 32) {
    gload_lds16(qh + gA0 + kb, Ah + lo0);
    gload_lds16(qh + gA1 + kb, Ah + lo1);
    gload_lds16(ql + gA0 + kb, Al + lo0);
    gload_lds16(ql + gA1 + kb, Al + lo1);
    gload_lds16(kh + gB0 + kb, Bh + lo0);
    gload_lds16(kh + gB1 + kb, Bh + lo1);
    gload_lds16(kl + gB0 + kb, Bl + lo0);
    gload_lds16(kl + gB1 + kb, Bl + lo1);
    __syncthreads();
    short8 afh[4], afl[4], bfh[4], bfl[4];
#pragma unroll
    for (int t = 0; t < 4; ++t) {
      int m = wm + (t << 4) + fm;
      int sa = ((m << 2) + (quad ^ ((m >> 1) & 3))) << 3;
      afh[t] = *(const short8*)&Ah[sa];
      afl[t] = *(const short8*)&Al[sa];
      int n = wn + (t << 4) + fm;
      int sb = ((n << 2) + (quad ^ ((n >> 1) & 3))) << 3;
      bfh[t] = *(const short8*)&Bh[sb];
      bfl[t] = *(const short8*)&Bl[sb];
    }
#pragma unroll
    for (int mi = 0; mi < 4; ++mi)
#pragma unroll
      for (int ni = 0; ni < 4; ++ni) {
        acc[mi][ni] = __builtin_amdgcn_mfma_f32_16x16x32_bf16(
            afh[mi], bfh[ni], acc[mi][ni], 0, 0, 0);
        acc[mi][ni] = __builtin_amdgcn_mfma_f32_16x16x32_bf16(
            afh[mi], bfl[ni], acc[mi][ni], 0, 0, 0);
        acc[mi][ni] = __builtin_amdgcn_mfma_f32_16x16x32_bf16(
            afl[mi], bfh[ni], acc[mi][ni], 0, 0, 0);
      }
    __syncthreads();
  }

  float* Cp = sim + (long)z * NN_ * NN_;
#pragma unroll
  for (int mi = 0; mi < 4; ++mi) {
#pragma unroll
    for (int ni = 0; ni < 4; ++ni) {
      int m = m0 + wm + (mi << 4) + (quad << 2);
      int n = n0 + wn + (ni << 4) + fm;
      float* p = Cp + (long)m * NN_ + n;
      p[0] = acc[mi][ni][0];
      p[NN_] = acc[mi][ni][1];
      p[2 * NN_] = acc[mi][ni][2];
      p[3 * NN_] = acc[mi][ni][3];
    }
  }
}

// One WAVE per row, zero barriers (R4 structure). Pass-0 of the radix select
// replaced by an 8-probe ballot bisection on the TOP BYTE: the Gaussian keys
// put ~512/2048 keys into each of ~4 top-byte bins, so the histogram pass-0
// serialized ~512 same-address LDS atomics per wave; 8 probes of 32
// ballot+popc are far cheaper. Passes 1-3 keep the (low-contention) LDS
// histogram machinery verbatim. All register arrays: constant-index,
// fully-unrolled access only (R6 lesson: anything else spills to scratch).
__global__ __launch_bounds__(256) void select_scatter_kernel(
    const float* __restrict__ sim, const float* __restrict__ dirs_a,
    const float* __restrict__ dirs_b, float* __restrict__ P)
{
  const int wave = threadIdx.x >> 6;
  const int lane = threadIdx.x & 63;
  const int row = (blockIdx.x << 2) | wave;
  const int b = row >> 11;
  const float* srow = sim + (long)row * NN_;
  float* prow = P + (long)row * NN_;

  __shared__ unsigned int hist_s[4][256];
  __shared__ unsigned int ckey_s[4][KC_];
  __shared__ int cidx_s[4][KC_];
  __shared__ int eq_s[4][EQCAP];
  __shared__ float outp_s[4][KF_];
  __shared__ int outj_s[4][KF_];
  __shared__ float rowbuf_s[4][1024];
  __shared__ int cnt_s[4][2];

  unsigned int* hist = hist_s[wave];
  unsigned int* ckey = ckey_s[wave];
  int* cidx = cidx_s[wave];
  int* eqb = eq_s[wave];
  float* outp = outp_s[wave];
  int* outj = outj_s[wave];
  float* rowbuf = rowbuf_s[wave];
  int* cnt = cnt_s[wave];

  // row -> 32 monotone keys per lane (coalesced float4 loads)
  unsigned int key[32];
#pragma unroll
  for (int c = 0; c < 8; ++c) {
    float4 v = *(const float4*)(srow + (c << 8) + (lane << 2));
    key[(c << 2) + 0] = mono_u(v.x);
    key[(c << 2) + 1] = mono_u(v.y);
    key[(c << 2) + 2] = mono_u(v.z);
    key[(c << 2) + 3] = mono_u(v.w);
  }

  // ---- pass 0: top-byte bisection (8 probes, ballot-popcount) ----
  // invariant: count(top8 >= blo) >= 128 (blo=0 -> 2048), count(>= bhi) < 128
  unsigned int blo = 0u, bhi = 256u;
#pragma unroll
  for (int it = 0; it < 8; ++it) {
    unsigned int mid = (blo + bhi) >> 1;
    int c = 0;
#pragma unroll
    for (int i = 0; i < 32; ++i)
      c += __popcll(__ballot((key[i] >> 24) >= mid));
    if (c >= KC_) blo = mid; else bhi = mid;
  }
  int cgt8 = 0;
#pragma unroll
  for (int i = 0; i < 32; ++i)
    cgt8 += __popcll(__ballot((key[i] >> 24) > blo));
  unsigned int prefix = blo << 24, pmask = 0xFF000000u;
  int need = KC_ - cgt8;  // >= 1

  // ---- passes 1-3: low-contention LDS radix histogram (R4 machinery) ----
  for (int pass = 1; pass < 4; ++pass) {
    const int sh = 24 - (pass << 3);
    uint4 z4; z4.x = z4.y = z4.z = z4.w = 0u;
    *(uint4*)&hist[lane << 2] = z4;
#pragma unroll
    for (int i = 0; i < 32; ++i) {
      unsigned int u = key[i];
      if ((u & pmask) == prefix) atomicAdd(&hist[(u >> sh) & 255u], 1u);
    }
    uint4 h = *(const uint4*)&hist[lane << 2];
    unsigned int s3 = h.w, s2 = h.z + s3, s1 = h.y + s2, s0 = h.x + s1;
    unsigned int tot = s0, incl = tot;
#pragma unroll
    for (int off = 1; off < 64; off <<= 1) {
      unsigned int y = __shfl_down(incl, off);
      incl += (lane + off < 64) ? y : 0u;
    }
    const unsigned int excl = incl - tot;
    unsigned int geq[4] = {s0 + excl, s1 + excl, s2 + excl, s3 + excl};
    unsigned int gt[4] = {s1 + excl, s2 + excl, s3 + excl, excl};
    int fbin = -1;
    unsigned int fgt = 0u;
#pragma unroll
    for (int i = 0; i < 4; ++i)
      if (fbin < 0 && geq[i] >= (unsigned)need && gt[i] < (unsigned)need) {
        fbin = (lane << 2) + i;
        fgt = gt[i];
      }
    unsigned long long mb = __ballot(fbin >= 0);
    int src = __ffsll(mb) - 1;
    int selbin = __shfl(fbin, src);
    unsigned int gtv = __shfl(fgt, src);
    prefix |= ((unsigned)(selbin & 255)) << sh;
    pmask |= 0xFFu << sh;
    need -= (int)gtv;
  }
  const unsigned int T = prefix;
  const int need_eq = need;
  const int count_gt = KC_ - need_eq;

  // ---- collect candidates ----
  if (lane == 0) { cnt[0] = 0; cnt[1] = 0; }
#pragma unroll
  for (int i = 0; i < 32; ++i) {
    unsigned int u = key[i];
    int col = ((i >> 2) << 8) + (lane << 2) + (i & 3);
    if (u > T) {
      int p = atomicAdd(&cnt[0], 1);
      ckey[p] = u;
      cidx[p] = col;
    } else if (u == T) {
      int p = atomicAdd(&cnt[1], 1);
      if (p < EQCAP) eqb[p] = col;
    }
  }
  int neq = cnt[1];
  if (lane == 0) {
    if (neq <= EQCAP) {  // typical: neq == 1
      for (int r = 0; r < need_eq; ++r) {
        int best = 0x7FFFFFFF, bi = 0;
        for (int t2 = 0; t2 < neq; ++t2)
          if (eqb[t2] < best) { best = eqb[t2]; bi = t2; }
        eqb[bi] = 0x7FFFFFFF;
        ckey[count_gt + r] = T;
        cidx[count_gt + r] = best;
      }
    } else {  // pathological mass-tie: rescan row in index order
      int r2 = 0;
      for (int j = 0; j < NN_ && r2 < need_eq; ++j)
        if (mono_u(srow[j]) == T) {
          ckey[count_gt + r2] = T;
          cidx[count_gt + r2] = j;
          ++r2;
        }
    }
  }

  // ---- angular mask (2 candidates/lane) ----
  const long dbase = (long)row * 3;
  const float dax = dirs_a[dbase + 0], day = dirs_a[dbase + 1],
              daz = dirs_a[dbase + 2];
  int j0 = cidx[lane], j1 = cidx[lane + 64];
  float va0 = inv_mono(ckey[lane]), va1 = inv_mono(ckey[lane + 64]);
  const float* db0 = dirs_b + ((long)(b << 11) + j0) * 3;
  float ca0 = dax * db0[0] + day * db0[1] + daz * db0[2];
  const float* db1 = dirs_b + ((long)(b << 11) + j1) * 3;
  float ca1 = dax * db1[0] + day * db1[1] + daz * db1[2];
  bool lm0 = ca0 >= 0.96592582628906831f;
  bool lm1 = ca1 >= 0.96592582628906831f;
  int ecnt = __popcll(__ballot(lm0)) + __popcll(__ballot(lm1));
  const bool all = (ecnt == 0);
  float v0 = (all || lm0) ? va0 : -INFINITY;
  float v1 = (all || lm1) ? va1 : -INFINITY;
  const int elig = all ? KC_ : ecnt;
  const int nk = elig < KF_ ? elig : KF_;

  // ---- fine top-16: iterative wave-wide argmax extraction ----
  for (int r = 0; r < nk; ++r) {
    float bvv; int bj, bs;
    if (v1 > v0 || (v1 == v0 && j1 < j0)) { bvv = v1; bj = j1; bs = lane + 64; }
    else { bvv = v0; bj = j0; bs = lane; }
#pragma unroll
    for (int off = 32; off > 0; off >>= 1) {
      float ov = __shfl_down(bvv, off);
      int oj = __shfl_down(bj, off);
      int os = __shfl_down(bs, off);
      if (ov > bvv || (ov == bvv && oj < bj)) { bvv = ov; bj = oj; bs = os; }
    }
    bvv = __shfl(bvv, 0); bj = __shfl(bj, 0); bs = __shfl(bs, 0);
    if (lane == 0) { outj[r] = bj; outp[r] = bvv; }
    if (bs == lane) v0 = -INFINITY;
    if (bs == lane + 64) v1 = -INFINITY;
  }

  // ---- softmax over kept logits (parallel over 16 lanes) ----
  const float invT = 1.0f / 0.07f;
  float mxl = outp[0] * invT;  // extraction is descending -> slot 0 is max
  float e = 0.f;
  int myj = 0;
  if (lane < nk) {
    e = __expf(outp[lane] * invT - mxl);
    myj = outj[lane];
  }
  float ssum = e;
#pragma unroll
  for (int off = 32; off > 0; off >>= 1) ssum += __shfl_xor(ssum, off);
  float pr = e / ssum;
  float s2 = pr;
#pragma unroll
  for (int off = 32; off > 0; off >>= 1) s2 += __shfl_xor(s2, off);
  const float outv = pr * (1.0f / (s2 + 1e-8f));

  // ---- zero + scatter + coalesced writeback, two 4KB halves ----
#pragma unroll
  for (int h = 0; h < 2; ++h) {
    float4 zf; zf.x = zf.y = zf.z = zf.w = 0.f;
#pragma unroll
    for (int q = 0; q < 4; ++q)
      *(float4*)&rowbuf[(q << 8) + (lane << 2)] = zf;
    if (lane < nk && (myj >> 10) == h) rowbuf[myj & 1023] = outv;
#pragma unroll
    for (int q = 0; q < 4; ++q) {
      float4 v = *(const float4*)&rowbuf[(q << 8) + (lane << 2)];
      *(float4*)(prow + (h << 10) + (q << 8) + (lane << 2)) = v;
    }
  }
}

extern "C" void kernel_launch(void* const* d_in, const int* in_sizes, int n_in,
                              void* d_out, int out_size, void* d_ws, size_t ws_size,
                              hipStream_t stream) {
  (void)in_sizes; (void)n_in; (void)out_size; (void)ws_size;
  const float* feat_a = (const float*)d_in[0];
  const float* feat_b = (const float*)d_in[1];
  const float* dirs_a = (const float*)d_in[2];
  const float* dirs_b = (const float*)d_in[3];
  const float* Wq = (const float*)d_in[4];
  const float* bq = (const float*)d_in[5];
  const float* Wk = (const float*)d_in[6];
  const float* bk = (const float*)d_in[7];
  float* P = (float*)d_out;

  __hip_bfloat16* qh = (__hip_bfloat16*)d_ws;
  __hip_bfloat16* ql = qh + (long)2 * NN_ * CC_;
  __hip_bfloat16* kh = ql + (long)2 * NN_ * CC_;
  __hip_bfloat16* kl = kh + (long)2 * NN_ * CC_;
  float* sim = (float*)(kl + (long)2 * NN_ * CC_);

  proj_mfma_kernel<<<dim3(CC_ / 64, (4 * NN_) / 64), 256, 0, stream>>>(
      feat_a, feat_b, Wq, bq, Wk, bk, qh, ql, kh, kl);

  sim_mfma_kernel<<<dim3(NN_ / 128, NN_ / 128, 2), 256, 0, stream>>>(
      qh, ql, kh, kl, sim);

  select_scatter_kernel<<<dim3((2 * NN_) / 4), 256, 0, stream>>>(
      sim, dirs_a, dirs_b, P);
}

// Round 8
// 138.393 us; speedup vs baseline: 2.2276x; 1.0087x over previous
//
#include <hip/hip_runtime.h>
#include <hip/hip_bf16.h>
#include <math.h>

#define NN_ 2048
#define CC_ 256
#define KC_ 128
#define KF_ 16
#define EQCAP 64

typedef __attribute__((ext_vector_type(8))) short short8;
typedef __attribute__((ext_vector_type(4))) float f32x4;
typedef __attribute__((ext_vector_type(16))) float f32x16;

__device__ __forceinline__ unsigned int mono_u(float f) {
  unsigned int u = __float_as_uint(f);
  return (u & 0x80000000u) ? ~u : (u | 0x80000000u);
}
__device__ __forceinline__ float inv_mono(unsigned int m) {
  unsigned int u = (m & 0x80000000u) ? (m ^ 0x80000000u) : ~m;
  return __uint_as_float(u);
}

__device__ __forceinline__ void gload_lds16(const void* g, void* l) {
  __builtin_amdgcn_global_load_lds(
      (const __attribute__((address_space(1))) void*)g,
      (__attribute__((address_space(3))) void*)l, 16, 0, 0);
}

__device__ __forceinline__ unsigned short bf16_bits(float v) {
  __hip_bfloat16 h = __float2bfloat16(v);  // RNE
  return *(unsigned short*)&h;
}
__device__ __forceinline__ float bf16_val(unsigned short u) {
  __hip_bfloat16 h = *(__hip_bfloat16*)&u;
  return __bfloat162float(h);
}

// Projection via split-bf16 MFMA (3 terms), fp32->h/l split fused into LDS
// staging. 64x64 tile, K=256, z folded into blockIdx.y. (unchanged from R4)
__global__ __launch_bounds__(256) void proj_mfma_kernel(
    const float* __restrict__ fa, const float* __restrict__ fb,
    const float* __restrict__ Wq, const float* __restrict__ bq,
    const float* __restrict__ Wk, const float* __restrict__ bk,
    __hip_bfloat16* __restrict__ qh, __hip_bfloat16* __restrict__ ql,
    __hip_bfloat16* __restrict__ kh, __hip_bfloat16* __restrict__ kl)
{
  __shared__ short Ah[64 * 32], Al[64 * 32], Bh[64 * 32], Bl[64 * 32];
  const int m0 = blockIdx.y * 64;
  const int z = m0 >> 12;
  const int mloc = m0 & 4095;
  const float* A = z ? fb : fa;
  const float* W = z ? Wk : Wq;
  const float* bias = z ? bk : bq;
  __hip_bfloat16* oh = z ? kh : qh;
  __hip_bfloat16* ol = z ? kl : ql;
  const int n0 = blockIdx.x * 64;
  const int tid = threadIdx.x;
  const int lane = tid & 63, wave = tid >> 6;
  const int wm = (wave & 1) << 5, wn = (wave >> 1) << 5;
  const int fm = lane & 15, quad = lane >> 4;

  const int r = tid >> 3;
  const int r2 = r + 32;
  const int c4 = (tid & 7) << 2;
  const int ck = c4 >> 3;
  const int soff = c4 & 7;
  const int iA0 = (((r << 2) + (ck ^ ((r >> 1) & 3))) << 3) + soff;
  const int iA1 = (((r2 << 2) + (ck ^ ((r2 >> 1) & 3))) << 3) + soff;

  f32x4 acc[2][2];
#pragma unroll
  for (int i = 0; i < 2; ++i)
#pragma unroll
    for (int j = 0; j < 2; ++j) acc[i][j] = (f32x4){0.f, 0.f, 0.f, 0.f};

  for (int kb = 0; kb < CC_; kb += 32) {
    float4 va0 = *(const float4*)(A + (long)(mloc + r) * CC_ + kb + c4);
    float4 va1 = *(const float4*)(A + (long)(mloc + r2) * CC_ + kb + c4);
    float4 vb0 = *(const float4*)(W + (long)(n0 + r) * CC_ + kb + c4);
    float4 vb1 = *(const float4*)(W + (long)(n0 + r2) * CC_ + kb + c4);
    __syncthreads();
    {
      const float* pv;
      float4 vv;
      vv = va0; pv = (const float*)&vv;
      uint2 hu, lu;
      unsigned short h0 = bf16_bits(pv[0]), h1 = bf16_bits(pv[1]),
                     h2 = bf16_bits(pv[2]), h3 = bf16_bits(pv[3]);
      hu.x = (unsigned)h0 | ((unsigned)h1 << 16);
      hu.y = (unsigned)h2 | ((unsigned)h3 << 16);
      lu.x = (unsigned)bf16_bits(pv[0] - bf16_val(h0)) |
             ((unsigned)bf16_bits(pv[1] - bf16_val(h1)) << 16);
      lu.y = (unsigned)bf16_bits(pv[2] - bf16_val(h2)) |
             ((unsigned)bf16_bits(pv[3] - bf16_val(h3)) << 16);
      *(uint2*)&Ah[iA0] = hu; *(uint2*)&Al[iA0] = lu;
      vv = va1; pv = (const float*)&vv;
      h0 = bf16_bits(pv[0]); h1 = bf16_bits(pv[1]);
      h2 = bf16_bits(pv[2]); h3 = bf16_bits(pv[3]);
      hu.x = (unsigned)h0 | ((unsigned)h1 << 16);
      hu.y = (unsigned)h2 | ((unsigned)h3 << 16);
      lu.x = (unsigned)bf16_bits(pv[0] - bf16_val(h0)) |
             ((unsigned)bf16_bits(pv[1] - bf16_val(h1)) << 16);
      lu.y = (unsigned)bf16_bits(pv[2] - bf16_val(h2)) |
             ((unsigned)bf16_bits(pv[3] - bf16_val(h3)) << 16);
      *(uint2*)&Ah[iA1] = hu; *(uint2*)&Al[iA1] = lu;
      vv = vb0; pv = (const float*)&vv;
      h0 = bf16_bits(pv[0]); h1 = bf16_bits(pv[1]);
      h2 = bf16_bits(pv[2]); h3 = bf16_bits(pv[3]);
      hu.x = (unsigned)h0 | ((unsigned)h1 << 16);
      hu.y = (unsigned)h2 | ((unsigned)h3 << 16);
      lu.x = (unsigned)bf16_bits(pv[0] - bf16_val(h0)) |
             ((unsigned)bf16_bits(pv[1] - bf16_val(h1)) << 16);
      lu.y = (unsigned)bf16_bits(pv[2] - bf16_val(h2)) |
             ((unsigned)bf16_bits(pv[3] - bf16_val(h3)) << 16);
      *(uint2*)&Bh[iA0] = hu; *(uint2*)&Bl[iA0] = lu;
      vv = vb1; pv = (const float*)&vv;
      h0 = bf16_bits(pv[0]); h1 = bf16_bits(pv[1]);
      h2 = bf16_bits(pv[2]); h3 = bf16_bits(pv[3]);
      hu.x = (unsigned)h0 | ((unsigned)h1 << 16);
      hu.y = (unsigned)h2 | ((unsigned)h3 << 16);
      lu.x = (unsigned)bf16_bits(pv[0] - bf16_val(h0)) |
             ((unsigned)bf16_bits(pv[1] - bf16_val(h1)) << 16);
      lu.y = (unsigned)bf16_bits(pv[2] - bf16_val(h2)) |
             ((unsigned)bf16_bits(pv[3] - bf16_val(h3)) << 16);
      *(uint2*)&Bh[iA1] = hu; *(uint2*)&Bl[iA1] = lu;
    }
    __syncthreads();
    short8 afh[2], afl[2], bfh[2], bfl[2];
#pragma unroll
    for (int t = 0; t < 2; ++t) {
      int m = wm + (t << 4) + fm;
      int sa = ((m << 2) + (quad ^ ((m >> 1) & 3))) << 3;
      afh[t] = *(const short8*)&Ah[sa];
      afl[t] = *(const short8*)&Al[sa];
      int n = wn + (t << 4) + fm;
      int sb = ((n << 2) + (quad ^ ((n >> 1) & 3))) << 3;
      bfh[t] = *(const short8*)&Bh[sb];
      bfl[t] = *(const short8*)&Bl[sb];
    }
#pragma unroll
    for (int mi = 0; mi < 2; ++mi)
#pragma unroll
      for (int ni = 0; ni < 2; ++ni) {
        acc[mi][ni] = __builtin_amdgcn_mfma_f32_16x16x32_bf16(
            afh[mi], bfh[ni], acc[mi][ni], 0, 0, 0);
        acc[mi][ni] = __builtin_amdgcn_mfma_f32_16x16x32_bf16(
            afh[mi], bfl[ni], acc[mi][ni], 0, 0, 0);
        acc[mi][ni] = __builtin_amdgcn_mfma_f32_16x16x32_bf16(
            afl[mi], bfh[ni], acc[mi][ni], 0, 0, 0);
      }
  }

#pragma unroll
  for (int mi = 0; mi < 2; ++mi)
#pragma unroll
    for (int ni = 0; ni < 2; ++ni) {
      int nn = n0 + wn + (ni << 4) + fm;
      float bval = bias[nn];
      int mrow = mloc + wm + (mi << 4) + (quad << 2);
#pragma unroll
      for (int reg = 0; reg < 4; ++reg) {
        float v = acc[mi][ni][reg] + bval;
        __hip_bfloat16 h = __float2bfloat16(v);
        long idx = (long)(mrow + reg) * CC_ + nn;
        oh[idx] = h;
        ol[idx] = __float2bfloat16(v - __bfloat162float(h));
      }
    }
}

// sim[z] = qh@kh^T + qh@kl^T + ql@kh^T via mfma_f32_32x32x16_bf16, BK=64:
// 4 K-iters, 8 barriers, 48 32x32-MFMA per iter per wave (vs 384 16x16 total).
// A/B frag: [m=lane&31][k=(lane>>5)*8+j] (extrapolates verified 16x16 rule);
// C/D: col=lane&31, row=(reg&3)+8*(reg>>2)+4*(lane>>5) (HW-verified m74/m101).
// LDS 64KB/block: 8-chunk XOR swizzle slot(m,c)=m*8+(c^(m&7)).
__global__ __launch_bounds__(256) void sim_mfma_kernel(
    const __hip_bfloat16* __restrict__ qh, const __hip_bfloat16* __restrict__ ql,
    const __hip_bfloat16* __restrict__ kh, const __hip_bfloat16* __restrict__ kl,
    float* __restrict__ sim)
{
  __shared__ short Ah[128 * 64], Al[128 * 64], Bh[128 * 64], Bl[128 * 64];
  const int z = blockIdx.z;
  const long off = (long)z * NN_ * CC_;
  const int m0 = blockIdx.y * 128, n0 = blockIdx.x * 128;
  const int tid = threadIdx.x;
  const int lane = tid & 63, wave = tid >> 6;
  const int wm = (wave & 1) << 6, wn = (wave >> 1) << 6;
  const int l31 = lane & 31, lh = lane >> 5;

  // staging: slot s holds row r=s>>3, stored-chunk cs=s&7 whose global chunk
  // is cs^(r&7). 4 rounds x 4 arrays per k-iter. (gload_lds dest is
  // wave-uniform base + lane*16 -> swizzle folded into the GLOBAL address.)
  int rs[4], cs[4];
#pragma unroll
  for (int t = 0; t < 4; ++t) {
    int s = (t << 8) + tid;
    rs[t] = s >> 3;
    cs[t] = (((s & 7) ^ ((s >> 3) & 7)) << 3);
  }

  f32x16 acc[2][2];
#pragma unroll
  for (int i = 0; i < 2; ++i)
#pragma unroll
    for (int j = 0; j < 2; ++j)
#pragma unroll
      for (int r = 0; r < 16; ++r) acc[i][j][r] = 0.f;

  for (int kb = 0; kb < CC_; kb += 64) {
#pragma unroll
    for (int t = 0; t < 4; ++t) {
      const int s8 = (((t << 8) + tid) << 3);
      const long gA = (long)(m0 + rs[t]) * CC_ + kb + cs[t] + off;
      const long gB = (long)(n0 + rs[t]) * CC_ + kb + cs[t] + off;
      gload_lds16(qh + gA, &Ah[s8]);
      gload_lds16(ql + gA, &Al[s8]);
      gload_lds16(kh + gB, &Bh[s8]);
      gload_lds16(kl + gB, &Bl[s8]);
    }
    __syncthreads();
#pragma unroll
    for (int ks = 0; ks < 4; ++ks) {      // K=16 steps within the 64-chunk
      const int cc = (ks << 1) + lh;      // chunk index 0..7
      short8 afh[2], afl[2], bfh[2], bfl[2];
#pragma unroll
      for (int tm = 0; tm < 2; ++tm) {
        int m = wm + (tm << 5) + l31;
        int sa = ((m << 3) + (cc ^ (m & 7))) << 3;
        afh[tm] = *(const short8*)&Ah[sa];
        afl[tm] = *(const short8*)&Al[sa];
        int n = wn + (tm << 5) + l31;
        int sb = ((n << 3) + (cc ^ (n & 7))) << 3;
        bfh[tm] = *(const short8*)&Bh[sb];
        bfl[tm] = *(const short8*)&Bl[sb];
      }
#pragma unroll
      for (int mi = 0; mi < 2; ++mi)
#pragma unroll
        for (int ni = 0; ni < 2; ++ni) {
          acc[mi][ni] = __builtin_amdgcn_mfma_f32_32x32x16_bf16(
              afh[mi], bfh[ni], acc[mi][ni], 0, 0, 0);
          acc[mi][ni] = __builtin_amdgcn_mfma_f32_32x32x16_bf16(
              afh[mi], bfl[ni], acc[mi][ni], 0, 0, 0);
          acc[mi][ni] = __builtin_amdgcn_mfma_f32_32x32x16_bf16(
              afl[mi], bfh[ni], acc[mi][ni], 0, 0, 0);
        }
    }
    __syncthreads();
  }

  float* Cp = sim + (long)z * NN_ * NN_;
  const int rowg = lh << 2;  // 4*(lane>>5)
#pragma unroll
  for (int mi = 0; mi < 2; ++mi) {
#pragma unroll
    for (int ni = 0; ni < 2; ++ni) {
      const int ccol = n0 + wn + (ni << 5) + l31;
      const int mbase = m0 + wm + (mi << 5) + rowg;
#pragma unroll
      for (int reg = 0; reg < 16; ++reg) {
        int mrow = mbase + (reg & 3) + ((reg >> 2) << 3);
        Cp[(long)mrow * NN_ + ccol] = acc[mi][ni][reg];
      }
    }
  }
}

// One WAVE per row, zero barriers (unchanged from R7: pass-0 top-byte
// bisection + passes 1-3 LDS radix histogram).
__global__ __launch_bounds__(256) void select_scatter_kernel(
    const float* __restrict__ sim, const float* __restrict__ dirs_a,
    const float* __restrict__ dirs_b, float* __restrict__ P)
{
  const int wave = threadIdx.x >> 6;
  const int lane = threadIdx.x & 63;
  const int row = (blockIdx.x << 2) | wave;
  const int b = row >> 11;
  const float* srow = sim + (long)row * NN_;
  float* prow = P + (long)row * NN_;

  __shared__ unsigned int hist_s[4][256];
  __shared__ unsigned int ckey_s[4][KC_];
  __shared__ int cidx_s[4][KC_];
  __shared__ int eq_s[4][EQCAP];
  __shared__ float outp_s[4][KF_];
  __shared__ int outj_s[4][KF_];
  __shared__ float rowbuf_s[4][1024];
  __shared__ int cnt_s[4][2];

  unsigned int* hist = hist_s[wave];
  unsigned int* ckey = ckey_s[wave];
  int* cidx = cidx_s[wave];
  int* eqb = eq_s[wave];
  float* outp = outp_s[wave];
  int* outj = outj_s[wave];
  float* rowbuf = rowbuf_s[wave];
  int* cnt = cnt_s[wave];

  unsigned int key[32];
#pragma unroll
  for (int c = 0; c < 8; ++c) {
    float4 v = *(const float4*)(srow + (c << 8) + (lane << 2));
    key[(c << 2) + 0] = mono_u(v.x);
    key[(c << 2) + 1] = mono_u(v.y);
    key[(c << 2) + 2] = mono_u(v.z);
    key[(c << 2) + 3] = mono_u(v.w);
  }

  // ---- pass 0: top-byte bisection (8 probes, ballot-popcount) ----
  unsigned int blo = 0u, bhi = 256u;
#pragma unroll
  for (int it = 0; it < 8; ++it) {
    unsigned int mid = (blo + bhi) >> 1;
    int c = 0;
#pragma unroll
    for (int i = 0; i < 32; ++i)
      c += __popcll(__ballot((key[i] >> 24) >= mid));
    if (c >= KC_) blo = mid; else bhi = mid;
  }
  int cgt8 = 0;
#pragma unroll
  for (int i = 0; i < 32; ++i)
    cgt8 += __popcll(__ballot((key[i] >> 24) > blo));
  unsigned int prefix = blo << 24, pmask = 0xFF000000u;
  int need = KC_ - cgt8;  // >= 1

  // ---- passes 1-3: low-contention LDS radix histogram ----
  for (int pass = 1; pass < 4; ++pass) {
    const int sh = 24 - (pass << 3);
    uint4 z4; z4.x = z4.y = z4.z = z4.w = 0u;
    *(uint4*)&hist[lane << 2] = z4;
#pragma unroll
    for (int i = 0; i < 32; ++i) {
      unsigned int u = key[i];
      if ((u & pmask) == prefix) atomicAdd(&hist[(u >> sh) & 255u], 1u);
    }
    uint4 h = *(const uint4*)&hist[lane << 2];
    unsigned int s3 = h.w, s2 = h.z + s3, s1 = h.y + s2, s0 = h.x + s1;
    unsigned int tot = s0, incl = tot;
#pragma unroll
    for (int off = 1; off < 64; off <<= 1) {
      unsigned int y = __shfl_down(incl, off);
      incl += (lane + off < 64) ? y : 0u;
    }
    const unsigned int excl = incl - tot;
    unsigned int geq[4] = {s0 + excl, s1 + excl, s2 + excl, s3 + excl};
    unsigned int gt[4] = {s1 + excl, s2 + excl, s3 + excl, excl};
    int fbin = -1;
    unsigned int fgt = 0u;
#pragma unroll
    for (int i = 0; i < 4; ++i)
      if (fbin < 0 && geq[i] >= (unsigned)need && gt[i] < (unsigned)need) {
        fbin = (lane << 2) + i;
        fgt = gt[i];
      }
    unsigned long long mb = __ballot(fbin >= 0);
    int src = __ffsll(mb) - 1;
    int selbin = __shfl(fbin, src);
    unsigned int gtv = __shfl(fgt, src);
    prefix |= ((unsigned)(selbin & 255)) << sh;
    pmask |= 0xFFu << sh;
    need -= (int)gtv;
  }
  const unsigned int T = prefix;
  const int need_eq = need;
  const int count_gt = KC_ - need_eq;

  // ---- collect candidates ----
  if (lane == 0) { cnt[0] = 0; cnt[1] = 0; }
#pragma unroll
  for (int i = 0; i < 32; ++i) {
    unsigned int u = key[i];
    int col = ((i >> 2) << 8) + (lane << 2) + (i & 3);
    if (u > T) {
      int p = atomicAdd(&cnt[0], 1);
      ckey[p] = u;
      cidx[p] = col;
    } else if (u == T) {
      int p = atomicAdd(&cnt[1], 1);
      if (p < EQCAP) eqb[p] = col;
    }
  }
  int neq = cnt[1];
  if (lane == 0) {
    if (neq <= EQCAP) {  // typical: neq == 1
      for (int r = 0; r < need_eq; ++r) {
        int best = 0x7FFFFFFF, bi = 0;
        for (int t2 = 0; t2 < neq; ++t2)
          if (eqb[t2] < best) { best = eqb[t2]; bi = t2; }
        eqb[bi] = 0x7FFFFFFF;
        ckey[count_gt + r] = T;
        cidx[count_gt + r] = best;
      }
    } else {  // pathological mass-tie: rescan row in index order
      int r2 = 0;
      for (int j = 0; j < NN_ && r2 < need_eq; ++j)
        if (mono_u(srow[j]) == T) {
          ckey[count_gt + r2] = T;
          cidx[count_gt + r2] = j;
          ++r2;
        }
    }
  }

  // ---- angular mask (2 candidates/lane) ----
  const long dbase = (long)row * 3;
  const float dax = dirs_a[dbase + 0], day = dirs_a[dbase + 1],
              daz = dirs_a[dbase + 2];
  int j0 = cidx[lane], j1 = cidx[lane + 64];
  float va0 = inv_mono(ckey[lane]), va1 = inv_mono(ckey[lane + 64]);
  const float* db0 = dirs_b + ((long)(b << 11) + j0) * 3;
  float ca0 = dax * db0[0] + day * db0[1] + daz * db0[2];
  const float* db1 = dirs_b + ((long)(b << 11) + j1) * 3;
  float ca1 = dax * db1[0] + day * db1[1] + daz * db1[2];
  bool lm0 = ca0 >= 0.96592582628906831f;
  bool lm1 = ca1 >= 0.96592582628906831f;
  int ecnt = __popcll(__ballot(lm0)) + __popcll(__ballot(lm1));
  const bool all = (ecnt == 0);
  float v0 = (all || lm0) ? va0 : -INFINITY;
  float v1 = (all || lm1) ? va1 : -INFINITY;
  const int elig = all ? KC_ : ecnt;
  const int nk = elig < KF_ ? elig : KF_;

  // ---- fine top-16: iterative wave-wide argmax extraction ----
  for (int r = 0; r < nk; ++r) {
    float bvv; int bj, bs;
    if (v1 > v0 || (v1 == v0 && j1 < j0)) { bvv = v1; bj = j1; bs = lane + 64; }
    else { bvv = v0; bj = j0; bs = lane; }
#pragma unroll
    for (int off = 32; off > 0; off >>= 1) {
      float ov = __shfl_down(bvv, off);
      int oj = __shfl_down(bj, off);
      int os = __shfl_down(bs, off);
      if (ov > bvv || (ov == bvv && oj < bj)) { bvv = ov; bj = oj; bs = os; }
    }
    bvv = __shfl(bvv, 0); bj = __shfl(bj, 0); bs = __shfl(bs, 0);
    if (lane == 0) { outj[r] = bj; outp[r] = bvv; }
    if (bs == lane) v0 = -INFINITY;
    if (bs == lane + 64) v1 = -INFINITY;
  }

  // ---- softmax over kept logits (parallel over 16 lanes) ----
  const float invT = 1.0f / 0.07f;
  float mxl = outp[0] * invT;
  float e = 0.f;
  int myj = 0;
  if (lane < nk) {
    e = __expf(outp[lane] * invT - mxl);
    myj = outj[lane];
  }
  float ssum = e;
#pragma unroll
  for (int off = 32; off > 0; off >>= 1) ssum += __shfl_xor(ssum, off);
  float pr = e / ssum;
  float s2 = pr;
#pragma unroll
  for (int off = 32; off > 0; off >>= 1) s2 += __shfl_xor(s2, off);
  const float outv = pr * (1.0f / (s2 + 1e-8f));

  // ---- zero + scatter + coalesced writeback, two 4KB halves ----
#pragma unroll
  for (int h = 0; h < 2; ++h) {
    float4 zf; zf.x = zf.y = zf.z = zf.w = 0.f;
#pragma unroll
    for (int q = 0; q < 4; ++q)
      *(float4*)&rowbuf[(q << 8) + (lane << 2)] = zf;
    if (lane < nk && (myj >> 10) == h) rowbuf[myj & 1023] = outv;
#pragma unroll
    for (int q = 0; q < 4; ++q) {
      float4 v = *(const float4*)&rowbuf[(q << 8) + (lane << 2)];
      *(float4*)(prow + (h << 10) + (q << 8) + (lane << 2)) = v;
    }
  }
}

extern "C" void kernel_launch(void* const* d_in, const int* in_sizes, int n_in,
                              void* d_out, int out_size, void* d_ws, size_t ws_size,
                              hipStream_t stream) {
  (void)in_sizes; (void)n_in; (void)out_size; (void)ws_size;
  const float* feat_a = (const float*)d_in[0];
  const float* feat_b = (const float*)d_in[1];
  const float* dirs_a = (const float*)d_in[2];
  const float* dirs_b = (const float*)d_in[3];
  const float* Wq = (const float*)d_in[4];
  const float* bq = (const float*)d_in[5];
  const float* Wk = (const float*)d_in[6];
  const float* bk = (const float*)d_in[7];
  float* P = (float*)d_out;

  __hip_bfloat16* qh = (__hip_bfloat16*)d_ws;
  __hip_bfloat16* ql = qh + (long)2 * NN_ * CC_;
  __hip_bfloat16* kh = ql + (long)2 * NN_ * CC_;
  __hip_bfloat16* kl = kh + (long)2 * NN_ * CC_;
  float* sim = (float*)(kl + (long)2 * NN_ * CC_);

  proj_mfma_kernel<<<dim3(CC_ / 64, (4 * NN_) / 64), 256, 0, stream>>>(
      feat_a, feat_b, Wq, bq, Wk, bk, qh, ql, kh, kl);

  sim_mfma_kernel<<<dim3(NN_ / 128, NN_ / 128, 2), 256, 0, stream>>>(
      qh, ql, kh, kl, sim);

  select_scatter_kernel<<<dim3((2 * NN_) / 4), 256, 0, stream>>>(
      sim, dirs_a, dirs_b, P);
}